// Round 1
// baseline (624.083 us; speedup 1.0000x reference)
//
#include <hip/hip_runtime.h>
#include <hip/hip_bf16.h>

#define NB 16
#define DIMD 96
#define VOX 884736        // 96*96*96
#define NPTS 4096
#define CHUNK 1024
#define NCHUNK 864        // VOX / CHUNK

// ---------------- point extraction ----------------

__global__ __launch_bounds__(256) void count_kernel(const float* __restrict__ vol,
                                                    int* __restrict__ counts) {
    int blk = blockIdx.x;  // b*NCHUNK + c
    const float4* v4 = (const float4*)(vol + (size_t)blk * CHUNK);
    float4 v = v4[threadIdx.x];
    int cnt = (v.x > 0.5f) + (v.y > 0.5f) + (v.z > 0.5f) + (v.w > 0.5f);
    for (int off = 32; off; off >>= 1) cnt += __shfl_down(cnt, off, 64);
    __shared__ int s[4];
    if ((threadIdx.x & 63) == 0) s[threadIdx.x >> 6] = cnt;
    __syncthreads();
    if (threadIdx.x == 0) counts[blk] = s[0] + s[1] + s[2] + s[3];
}

__global__ __launch_bounds__(1024) void scan_kernel(const int* __restrict__ counts,
                                                    int* __restrict__ prefix,
                                                    int* __restrict__ totals) {
    __shared__ int s[1024];
    int b = blockIdx.x, t = threadIdx.x;
    int v = (t < NCHUNK) ? counts[b * NCHUNK + t] : 0;
    s[t] = v;
    __syncthreads();
    for (int off = 1; off < 1024; off <<= 1) {
        int x = (t >= off) ? s[t - off] : 0;
        __syncthreads();
        s[t] += x;
        __syncthreads();
    }
    if (t < NCHUNK) prefix[b * NCHUNK + t] = s[t] - v;   // exclusive
    if (t == NCHUNK - 1) totals[b] = s[t];
}

__global__ __launch_bounds__(256) void points_kernel(const float* __restrict__ vol,
                                                     const int* __restrict__ prefix,
                                                     const int* __restrict__ totals,
                                                     float* __restrict__ pts) {
    int gid = blockIdx.x * 256 + threadIdx.x;  // 0 .. NB*NPTS
    int b = gid >> 12;
    int p = gid & (NPTS - 1);
    int n = totals[b];
    float px = 0.f, py = 0.f, pz = 0.f;
    if (n > 0) {
        int k;
        if (n >= NPTS) {
            // replicate jnp fp32 exactly: trunc( p * (n-1) / 4095 )
            float t = (float)p * ((float)n - 1.0f);
            t = t / 4095.0f;
            k = (int)t;
            if (k > n - 1) k = n - 1;
            if (k < 0) k = 0;
        } else {
            k = p % n;
        }
        const int* pref = prefix + b * NCHUNK;
        int lo = 0, hi = NCHUNK - 1;
        while (lo < hi) {
            int mid = (lo + hi + 1) >> 1;
            if (pref[mid] <= k) lo = mid; else hi = mid - 1;
        }
        int r = k - pref[lo];
        const float4* v4 = (const float4*)(vol + (size_t)b * VOX + (size_t)lo * CHUNK);
        int flat = 0, acc = 0;
        for (int i = 0; i < CHUNK / 4; i++) {
            float4 q = v4[i];
            int c0 = q.x > 0.5f, c1 = q.y > 0.5f, c2 = q.z > 0.5f, c3 = q.w > 0.5f;
            int s4 = c0 + c1 + c2 + c3;
            if (acc + s4 > r) {
                int rr = r - acc;
                int j;
                if (c0 && rr == 0) j = 0;
                else {
                    rr -= c0;
                    if (c1 && rr == 0) j = 1;
                    else {
                        rr -= c1;
                        if (c2 && rr == 0) j = 2; else j = 3;
                    }
                }
                flat = lo * CHUNK + i * 4 + j;
                break;
            }
            acc += s4;
        }
        int dd = flat / 9216;           // 96*96
        int rem = flat - dd * 9216;
        int hh = rem / 96;
        int ww = rem - hh * 96;
        px = (float)dd / 95.0f * 2.0f - 1.0f;
        py = (float)hh / 95.0f * 2.0f - 1.0f;
        pz = (float)ww / 95.0f * 2.0f - 1.0f;
    }
    pts[((size_t)b * 3 + 0) * NPTS + p] = px;
    pts[((size_t)b * 3 + 1) * NPTS + p] = py;
    pts[((size_t)b * 3 + 2) * NPTS + p] = pz;
}

// ---------------- layer 1 (C=3 -> 64) ----------------

__global__ __launch_bounds__(256) void conv1_kernel(const float* __restrict__ pts,
                                                    const float* __restrict__ w1,
                                                    float* __restrict__ out) {
    int gid = blockIdx.x * 256 + threadIdx.x;
    int b = gid >> 12, p = gid & (NPTS - 1);
    float x0 = pts[((size_t)b * 3 + 0) * NPTS + p];
    float x1 = pts[((size_t)b * 3 + 1) * NPTS + p];
    float x2 = pts[((size_t)b * 3 + 2) * NPTS + p];
    float* ob = out + (size_t)b * 64 * NPTS + p;
    #pragma unroll
    for (int o = 0; o < 64; o++) {
        float acc = w1[o * 3 + 0] * x0 + w1[o * 3 + 1] * x1 + w1[o * 3 + 2] * x2;
        ob[(size_t)o * NPTS] = acc;
    }
}

// ---------------- generic tiled GEMM: out[b,o,p] = sum_c w[o,c]*x[b,c,p] ----------------

template <int CIN>
__global__ __launch_bounds__(256) void conv_gemm(const float* __restrict__ x,
                                                 const float* __restrict__ w,
                                                 float* __restrict__ out, int O) {
    __shared__ float sw[16][65];
    __shared__ float sx[16][64];
    int b = blockIdx.z;
    int o0 = blockIdx.y * 64;
    int p0 = blockIdx.x * 64;
    int tid = threadIdx.x;
    int tx = tid & 15, ty = tid >> 4;
    const float* xb = x + (size_t)b * CIN * NPTS;
    float acc[4][4] = {};
    for (int c0 = 0; c0 < CIN; c0 += 16) {
        {
            int oo = tid >> 2;
            int kc4 = (tid & 3) * 4;
            float4 wv = *(const float4*)(w + (size_t)(o0 + oo) * CIN + c0 + kc4);
            sw[kc4 + 0][oo] = wv.x;
            sw[kc4 + 1][oo] = wv.y;
            sw[kc4 + 2][oo] = wv.z;
            sw[kc4 + 3][oo] = wv.w;
        }
        {
            int kc = tid >> 4;
            int pp4 = (tid & 15) * 4;
            float4 xv = *(const float4*)(xb + (size_t)(c0 + kc) * NPTS + p0 + pp4);
            *(float4*)&sx[kc][pp4] = xv;
        }
        __syncthreads();
        #pragma unroll
        for (int k = 0; k < 16; k++) {
            float a0 = sw[k][ty * 4 + 0];
            float a1 = sw[k][ty * 4 + 1];
            float a2 = sw[k][ty * 4 + 2];
            float a3 = sw[k][ty * 4 + 3];
            float4 xv = *(const float4*)&sx[k][tx * 4];
            acc[0][0] += a0 * xv.x; acc[0][1] += a0 * xv.y; acc[0][2] += a0 * xv.z; acc[0][3] += a0 * xv.w;
            acc[1][0] += a1 * xv.x; acc[1][1] += a1 * xv.y; acc[1][2] += a1 * xv.z; acc[1][3] += a1 * xv.w;
            acc[2][0] += a2 * xv.x; acc[2][1] += a2 * xv.y; acc[2][2] += a2 * xv.z; acc[2][3] += a2 * xv.w;
            acc[3][0] += a3 * xv.x; acc[3][1] += a3 * xv.y; acc[3][2] += a3 * xv.z; acc[3][3] += a3 * xv.w;
        }
        __syncthreads();
    }
    #pragma unroll
    for (int i = 0; i < 4; i++) {
        float4 v = make_float4(acc[i][0], acc[i][1], acc[i][2], acc[i][3]);
        *(float4*)(out + (size_t)b * O * NPTS + (size_t)(o0 + ty * 4 + i) * NPTS + p0 + tx * 4) = v;
    }
}

// ---------------- GroupNorm ----------------

__global__ __launch_bounds__(256) void gn_stats(const float* __restrict__ x,
                                                float* __restrict__ stats, int C) {
    int b = blockIdx.x >> 3;
    int g = blockIdx.x & 7;
    int L = (C >> 3) * NPTS;
    const float4* base = (const float4*)(x + (size_t)b * C * NPTS + (size_t)g * L);
    int n4 = L >> 2;
    float sum = 0.f, sq = 0.f;
    for (int i = threadIdx.x; i < n4; i += 256) {
        float4 v = base[i];
        sum += v.x + v.y + v.z + v.w;
        sq += v.x * v.x + v.y * v.y + v.z * v.z + v.w * v.w;
    }
    for (int off = 32; off; off >>= 1) {
        sum += __shfl_down(sum, off, 64);
        sq += __shfl_down(sq, off, 64);
    }
    __shared__ float ss[8];
    if ((threadIdx.x & 63) == 0) {
        ss[(threadIdx.x >> 6) * 2] = sum;
        ss[(threadIdx.x >> 6) * 2 + 1] = sq;
    }
    __syncthreads();
    if (threadIdx.x == 0) {
        float S = 0.f, Q = 0.f;
        for (int wv = 0; wv < 4; wv++) { S += ss[wv * 2]; Q += ss[wv * 2 + 1]; }
        float inv = 1.0f / (float)L;
        float mu = S * inv;
        float var = Q * inv - mu * mu;
        if (var < 0.f) var = 0.f;
        float rstd = rsqrtf(var + 1e-5f);
        stats[(b * 8 + g) * 2] = mu;
        stats[(b * 8 + g) * 2 + 1] = rstd;
    }
}

__global__ __launch_bounds__(256) void gn_norm_relu(float* __restrict__ x,
                                                    const float* __restrict__ stats,
                                                    const float* __restrict__ gamma,
                                                    const float* __restrict__ beta, int C) {
    int i4 = blockIdx.x * 256 + threadIdx.x;     // float4 index
    int pc = i4 >> 10;                           // b*C + ch   (4096/4 float4 per channel)
    int ch = pc % C;
    int b = pc / C;
    int g = ch / (C >> 3);
    float mu = stats[(b * 8 + g) * 2];
    float rstd = stats[(b * 8 + g) * 2 + 1];
    float ga = gamma[ch] * rstd;
    float be = beta[ch] - mu * ga;
    float4* px = (float4*)x + i4;
    float4 v = *px;
    v.x = fmaxf(v.x * ga + be, 0.f);
    v.y = fmaxf(v.y * ga + be, 0.f);
    v.z = fmaxf(v.z * ga + be, 0.f);
    v.w = fmaxf(v.w * ga + be, 0.f);
    *px = v;
}

// ---------------- layer-4 norm+relu+maxpool fused ----------------

__global__ __launch_bounds__(256) void pool4_kernel(const float* __restrict__ x,
                                                    const float* __restrict__ stats,
                                                    const float* __restrict__ gamma,
                                                    const float* __restrict__ beta,
                                                    float* __restrict__ g) {
    int b = blockIdx.x >> 9;
    int c = blockIdx.x & 511;
    int grp = c >> 6;                 // 512/8 = 64 channels per group
    float mu = stats[(b * 8 + grp) * 2];
    float rstd = stats[(b * 8 + grp) * 2 + 1];
    float ga = gamma[c] * rstd;
    float be = beta[c] - mu * ga;
    const float4* base = (const float4*)(x + ((size_t)b * 512 + c) * NPTS);
    float m = 0.f;   // ReLU output is >= 0
    for (int i = threadIdx.x; i < NPTS / 4; i += 256) {
        float4 v = base[i];
        m = fmaxf(m, fmaxf(fmaxf(v.x * ga + be, v.y * ga + be), fmaxf(v.z * ga + be, v.w * ga + be)));
    }
    for (int off = 32; off; off >>= 1) m = fmaxf(m, __shfl_down(m, off, 64));
    __shared__ float ss[4];
    if ((threadIdx.x & 63) == 0) ss[threadIdx.x >> 6] = m;
    __syncthreads();
    if (threadIdx.x == 0)
        g[b * 512 + c] = fmaxf(fmaxf(fmaxf(ss[0], ss[1]), fmaxf(ss[2], ss[3])), 0.f);
}

// ---------------- FC head ----------------

__global__ __launch_bounds__(128) void head_kernel(const float* __restrict__ g,
                                                   const float* __restrict__ fc1w,
                                                   const float* __restrict__ fc1b,
                                                   const float* __restrict__ fc2w,
                                                   const float* __restrict__ fc2b,
                                                   float* __restrict__ out) {
    int b = blockIdx.x;
    int o = threadIdx.x;   // 128
    __shared__ float sg[512];
    for (int i = threadIdx.x; i < 512; i += 128) sg[i] = g[b * 512 + i];
    __syncthreads();
    float acc = fc1b[o];
    for (int c = 0; c < 512; c++) acc += sg[c] * fc1w[o * 512 + c];
    float h = fmaxf(acc, 0.f) * fc2w[o];
    for (int off = 32; off; off >>= 1) h += __shfl_down(h, off, 64);
    __shared__ float s2[2];
    if ((threadIdx.x & 63) == 0) s2[threadIdx.x >> 6] = h;
    __syncthreads();
    if (threadIdx.x == 0) out[b] = s2[0] + s2[1] + fc2b[0];
}

// ---------------- launch ----------------

extern "C" void kernel_launch(void* const* d_in, const int* in_sizes, int n_in,
                              void* d_out, int out_size, void* d_ws, size_t ws_size,
                              hipStream_t stream) {
    const float* vol  = (const float*)d_in[0];
    const float* w1   = (const float*)d_in[1];
    const float* gn1w = (const float*)d_in[2];
    const float* gn1b = (const float*)d_in[3];
    const float* w2   = (const float*)d_in[4];
    const float* gn2w = (const float*)d_in[5];
    const float* gn2b = (const float*)d_in[6];
    const float* w3   = (const float*)d_in[7];
    const float* gn3w = (const float*)d_in[8];
    const float* gn3b = (const float*)d_in[9];
    const float* w4   = (const float*)d_in[10];
    const float* gn4w = (const float*)d_in[11];
    const float* gn4b = (const float*)d_in[12];
    const float* fc1w = (const float*)d_in[13];
    const float* fc1b = (const float*)d_in[14];
    const float* fc2w = (const float*)d_in[15];
    const float* fc2b = (const float*)d_in[16];
    float* out = (float*)d_out;

    char* ws = (char*)d_ws;
    size_t cur = 0;
    auto alloc = [&](size_t bytes) -> void* {
        cur = (cur + 255) & ~(size_t)255;
        void* p = ws + cur;
        cur += bytes;
        return p;
    };
    int*   counts = (int*)alloc((size_t)NB * NCHUNK * 4);
    int*   prefix = (int*)alloc((size_t)NB * NCHUNK * 4);
    int*   totals = (int*)alloc(64);
    float* stats  = (float*)alloc((size_t)NB * 8 * 2 * 4);
    float* pts    = (float*)alloc((size_t)NB * 3 * NPTS * 4);
    float* gbuf   = (float*)alloc((size_t)NB * 512 * 4);
    float* bufB   = (float*)alloc((size_t)NB * 256 * NPTS * 4);   // x1 (64), x3 (256)
    float* bufA   = (float*)alloc((size_t)NB * 512 * NPTS * 4);   // x2 (128), x4 (512)

    // 1. points
    count_kernel<<<dim3(NB * NCHUNK), dim3(256), 0, stream>>>(vol, counts);
    scan_kernel<<<dim3(NB), dim3(1024), 0, stream>>>(counts, prefix, totals);
    points_kernel<<<dim3(NB * NPTS / 256), dim3(256), 0, stream>>>(vol, prefix, totals, pts);

    // 2. layer 1: 3 -> 64 (bufB)
    conv1_kernel<<<dim3(NB * NPTS / 256), dim3(256), 0, stream>>>(pts, w1, bufB);
    gn_stats<<<dim3(NB * 8), dim3(256), 0, stream>>>(bufB, stats, 64);
    gn_norm_relu<<<dim3(NB * 64 * 1024 / 256), dim3(256), 0, stream>>>(bufB, stats, gn1w, gn1b, 64);

    // 3. layer 2: 64 -> 128 (bufB -> bufA)
    conv_gemm<64><<<dim3(64, 2, NB), dim3(256), 0, stream>>>(bufB, w2, bufA, 128);
    gn_stats<<<dim3(NB * 8), dim3(256), 0, stream>>>(bufA, stats, 128);
    gn_norm_relu<<<dim3(NB * 128 * 1024 / 256), dim3(256), 0, stream>>>(bufA, stats, gn2w, gn2b, 128);

    // 4. layer 3: 128 -> 256 (bufA -> bufB)
    conv_gemm<128><<<dim3(64, 4, NB), dim3(256), 0, stream>>>(bufA, w3, bufB, 256);
    gn_stats<<<dim3(NB * 8), dim3(256), 0, stream>>>(bufB, stats, 256);
    gn_norm_relu<<<dim3(NB * 256 * 1024 / 256), dim3(256), 0, stream>>>(bufB, stats, gn3w, gn3b, 256);

    // 5. layer 4: 256 -> 512 (bufB -> bufA), GN stats, fused norm+relu+maxpool
    conv_gemm<256><<<dim3(64, 8, NB), dim3(256), 0, stream>>>(bufB, w4, bufA, 512);
    gn_stats<<<dim3(NB * 8), dim3(256), 0, stream>>>(bufA, stats, 512);
    pool4_kernel<<<dim3(NB * 512), dim3(256), 0, stream>>>(bufA, stats, gn4w, gn4b, gbuf);

    // 6. head
    head_kernel<<<dim3(NB), dim3(128), 0, stream>>>(gbuf, fc1w, fc1b, fc2w, fc2b, out);
}